// Round 5
// baseline (11082.503 us; speedup 1.0000x reference)
//
#include <hip/hip_runtime.h>
#include <hip/hip_bf16.h>
#include <hip/hip_fp16.h>

#define TT 2048
#define BB 64
#define HH 512
#define GG 2048  // 4H

typedef __attribute__((ext_vector_type(4))) float f32x4;
typedef __attribute__((ext_vector_type(8))) short short8;
typedef __attribute__((ext_vector_type(4))) short short4v;
typedef __attribute__((ext_vector_type(4))) unsigned u32x4;

static __device__ __forceinline__ short f2bf(float f) {
  unsigned u = __builtin_bit_cast(unsigned, f);
  u = (u + 0x7FFFu + ((u >> 16) & 1u)) >> 16;
  return (short)u;
}
static __device__ __forceinline__ float fsigmoid(float x) { return 1.0f / (1.0f + __expf(-x)); }
static __device__ __forceinline__ float ftanh(float x) {
  float e = __expf(2.0f * x);
  return 1.0f - 2.0f / (e + 1.0f);
}
static __device__ __forceinline__ float h2f(unsigned short u) {
  __half h = __builtin_bit_cast(__half, u);
  return __half2float(h);
}

// ---------------- fp32 -> bf16 convert ----------------
__global__ void cvt_bf16_kernel(const float4* __restrict__ in, short4v* __restrict__ outp, long n4) {
  long i = (long)blockIdx.x * blockDim.x + threadIdx.x;
  long stride = (long)gridDim.x * blockDim.x;
  for (; i < n4; i += stride) {
    float4 v = in[i];
    short4v o;
    o[0] = f2bf(v.x); o[1] = f2bf(v.y); o[2] = f2bf(v.z); o[3] = f2bf(v.w);
    outp[i] = o;
  }
}

// ---------------- phase 1: xpart = X @ W_ih^T + (b_ih + b_hh), f16 ----------------
// out layout: [t][bg(4)][cp(16)][thread(256)][slot(2)*4 + gate(4)] f16 (16B per thread)
__global__ __launch_bounds__(256) void gemm_xpart(
    const __hip_bfloat16* __restrict__ Abf, const __hip_bfloat16* __restrict__ Bbf,
    const float* __restrict__ bih, const float* __restrict__ bhh, __half* __restrict__ xout) {
  __shared__ __hip_bfloat16 As[128 * 64];
  __shared__ __hip_bfloat16 Bs[128 * 64];
  const int nwg = gridDim.x;
  const int bid = blockIdx.x;
  const int vb = (bid & 7) * (nwg >> 3) + (bid >> 3);
  const int mt = vb >> 4;
  const int nt = vb & 15;
  const size_t m0 = (size_t)mt * 128;
  const int n0 = nt * 128;
  const int tid = threadIdx.x;
  const int lane = tid & 63;
  const int w = tid >> 6;
  const int wm = w >> 1, wn = w & 1;
  const int g = lane >> 4;
  f32x4 acc[4][4] = {};
  for (int k0 = 0; k0 < 512; k0 += 64) {
#pragma unroll
    for (int i = 0; i < 4; i++) {
      const int slot = w * 4 + i;
      const int row = slot * 8 + (lane >> 3);
      const int segS = (lane & 7) ^ (row & 7);
      const __hip_bfloat16* ga = Abf + (m0 + row) * 512 + k0 + segS * 8;
      const __hip_bfloat16* gb = Bbf + (size_t)(n0 + row) * 512 + k0 + segS * 8;
      __builtin_amdgcn_global_load_lds(
          (const __attribute__((address_space(1))) unsigned*)(const void*)ga,
          (__attribute__((address_space(3))) unsigned*)(void*)(As + slot * 512), 16, 0, 0);
      __builtin_amdgcn_global_load_lds(
          (const __attribute__((address_space(1))) unsigned*)(const void*)gb,
          (__attribute__((address_space(3))) unsigned*)(void*)(Bs + slot * 512), 16, 0, 0);
    }
    __syncthreads();
#pragma unroll
    for (int kk = 0; kk < 2; kk++) {
      short8 av[4], bv[4];
#pragma unroll
      for (int f = 0; f < 4; f++) {
        const int row = wm * 64 + f * 16 + (lane & 15);
        av[f] = *(const short8*)(As + row * 64 + ((((kk << 2) + g) ^ (row & 7)) << 3));
      }
#pragma unroll
      for (int f = 0; f < 4; f++) {
        const int row = wn * 64 + f * 16 + (lane & 15);
        bv[f] = *(const short8*)(Bs + row * 64 + ((((kk << 2) + g) ^ (row & 7)) << 3));
      }
#pragma unroll
      for (int fi = 0; fi < 4; fi++)
#pragma unroll
        for (int fj = 0; fj < 4; fj++)
          acc[fi][fj] = __builtin_amdgcn_mfma_f32_16x16x32_bf16(av[fi], bv[fj], acc[fi][fj], 0, 0, 0);
    }
    __syncthreads();
  }
#pragma unroll
  for (int fj = 0; fj < 4; fj++) {
    const int n = n0 + wn * 64 + fj * 16 + (lane & 15);
    const float bias = bih[n] + bhh[n];
    const int q = n >> 9;        // gate
    const int hcol = n & 511;
    const int cpn = hcol >> 5;
    const int j = hcol & 31;
    const int wv = (j >> 2) & 3;
    const int g4v = j & 3;
    const int slot = j >> 4;
    const int thr = wv * 64 + g4v * 16;  // + b16 per element
#pragma unroll
    for (int fi = 0; fi < 4; fi++) {
      const size_t mrow = m0 + wm * 64 + fi * 16 + g * 4;
#pragma unroll
      for (int r = 0; r < 4; r++) {
        const size_t m = mrow + r;
        const size_t tt = m >> 6;
        const int bglob = (int)(m & 63);
        const int bgn = bglob >> 4;
        const int b16n = bglob & 15;
        const size_t idx = ((((tt * 4 + bgn) * 16 + cpn) * 256 + (size_t)(thr + b16n)) << 3) +
                           (size_t)(slot * 4 + q);
        xout[idx] = __float2half(acc[fi][fj][r] + bias);
      }
    }
  }
}

// ---------------- phase 2: persistent LSTM scan, tag-validated h exchange ----------------
// 64 blocks = [bg(4)][cp(16)] x 256 threads. Block owns 16 batches x 32 h-cols.
// h dword = (step_tag << 16) | bf16(h)  -- single-copy-atomic tag+data, no flags, 1 MALL RT.
// hbufT layout: [buf(2)][bg(4)][batch(16)][col(512) dwords]
__global__ __launch_bounds__(256, 1) void lstm_scan_kernel(
    const __half* __restrict__ xpart, const float* __restrict__ Whh,
    char* hbufT, float* __restrict__ outp) {
  __shared__ char Hs[16384];  // [b(16)][seg(64) x 16B untagged bf16], seg stored at (seg ^ (b&7))
  const int blk = blockIdx.x;
  const int bg = blk >> 4;
  const int cp = blk & 15;
  const int tid = threadIdx.x;
  const int lane = tid & 63;
  const int w = tid >> 6;
  const int b16 = lane & 15;
  const int g4 = lane >> 4;
  const int qr = b16 & 3;   // A-frag row -> gate
  const int jj = b16 >> 2;  // A-frag row -> col-in-tile
  const int colA = cp * 32 + w * 4 + g4;
  const int colB = cp * 32 + (w + 4) * 4 + g4;
  const int batchg = bg * 16 + b16;

  // ---- one-time: W_hh slices -> registers (bf16 A-frags) ----
  const int rowA = qr * 512 + cp * 32 + w * 4 + jj;
  const int rowB = qr * 512 + cp * 32 + (w + 4) * 4 + jj;
  short8 wA[16], wB[16];
#pragma unroll
  for (int kt = 0; kt < 16; kt++) {
    const float* pa = Whh + (size_t)rowA * 512 + kt * 32 + g4 * 8;
    const float* pb = Whh + (size_t)rowB * 512 + kt * 32 + g4 * 8;
    float4 a0 = *(const float4*)pa;
    float4 a1 = *(const float4*)(pa + 4);
    float4 b0 = *(const float4*)pb;
    float4 b1 = *(const float4*)(pb + 4);
    short8 va, vb;
    va[0] = f2bf(a0.x); va[1] = f2bf(a0.y); va[2] = f2bf(a0.z); va[3] = f2bf(a0.w);
    va[4] = f2bf(a1.x); va[5] = f2bf(a1.y); va[6] = f2bf(a1.z); va[7] = f2bf(a1.w);
    vb[0] = f2bf(b0.x); vb[1] = f2bf(b0.y); vb[2] = f2bf(b0.z); vb[3] = f2bf(b0.w);
    vb[4] = f2bf(b1.x); vb[5] = f2bf(b1.y); vb[6] = f2bf(b1.z); vb[7] = f2bf(b1.w);
    wA[kt] = va;
    wB[kt] = vb;
  }

  // xpart: 16B per thread per step, thread-linear
  const size_t xstride = (size_t)4 * 16 * 256 * 8;
  const __half* xbase = xpart + ((size_t)bg * 16 + cp) * 256 * 8 + (size_t)tid * 8;
  short8 xv = *(const short8*)(const void*)xbase;  // t = 0

  // consumer: thread loads 128B tagged = batch (tid>>4), tagged dwords (tid&15)*32 .. +31
  const unsigned long long hloadb =
      (unsigned long long)(uintptr_t)hbufT + (unsigned long long)(bg * 32768) +
      (unsigned long long)((tid >> 4) * 2048 + (tid & 15) * 128);
  char* wdst = Hs + (tid >> 4) * 1024;
  const int s0 = (tid & 15) * 4;
  const int bb7 = (tid >> 4) & 7;

  float cA = 0.f, cB = 0.f, hAv = 0.f, hBv = 0.f;

  for (int t = 0; t < TT; t++) {
    // prefetch next step's xpart
    const int tn = (t + 1 < TT) ? (t + 1) : (TT - 1);
    short8 xvn = *(const short8*)(const void*)(xbase + (size_t)tn * xstride);

    f32x4 accA = {0.f, 0.f, 0.f, 0.f};
    f32x4 accB = {0.f, 0.f, 0.f, 0.f};
    if (t > 0) {
      // --- acquire: load tagged h, validate per 16B chunk, reload stale chunks only ---
      const unsigned long long hb = hloadb + (unsigned long long)((t & 1) * 131072);
      const unsigned want = ((unsigned)t) << 16;
      u32x4 hv[8];
#pragma unroll
      for (int k = 0; k < 8; k++)
        asm volatile("global_load_dwordx4 %0, %1, off sc0 sc1"
                     : "=v"(hv[k]) : "v"(hb + (unsigned long long)(k * 16)));
      asm volatile("s_waitcnt vmcnt(0)" ::: "memory");
      unsigned badk = 0;
#pragma unroll
      for (int k = 0; k < 8; k++) {
        unsigned bad = ((hv[k][0] ^ want) | (hv[k][1] ^ want) | (hv[k][2] ^ want) |
                        (hv[k][3] ^ want)) & 0xFFFF0000u;
        badk |= (bad ? 1u : 0u) << k;
      }
      while (__any((int)badk)) {
#pragma unroll
        for (int k = 0; k < 8; k++)
          if (badk & (1u << k))
            asm volatile("global_load_dwordx4 %0, %1, off sc0 sc1"
                         : "=v"(hv[k]) : "v"(hb + (unsigned long long)(k * 16)));
        asm volatile("s_waitcnt vmcnt(0)" ::: "memory");
        badk = 0;
#pragma unroll
        for (int k = 0; k < 8; k++) {
          unsigned bad = ((hv[k][0] ^ want) | (hv[k][1] ^ want) | (hv[k][2] ^ want) |
                          (hv[k][3] ^ want)) & 0xFFFF0000u;
          badk |= (bad ? 1u : 0u) << k;
        }
      }
      __builtin_amdgcn_sched_barrier(0);
      // --- strip tags (v_perm) and stage to LDS (validation implies prev ds_reads done) ---
      unsigned ut[16];
#pragma unroll
      for (int i = 0; i < 16; i++) {
        unsigned lo = hv[i >> 1][(i & 1) * 2];
        unsigned hi = hv[i >> 1][(i & 1) * 2 + 1];
        ut[i] = __builtin_amdgcn_perm(hi, lo, 0x05040100u);
      }
#pragma unroll
      for (int p = 0; p < 4; p++) {
        u32x4 v = {ut[4 * p], ut[4 * p + 1], ut[4 * p + 2], ut[4 * p + 3]};
        *(u32x4*)(wdst + (((s0 + p) ^ bb7) << 4)) = v;
      }
      __syncthreads();
      // --- MFMA ---
#pragma unroll
      for (int kt = 0; kt < 16; kt++) {
        const int sp = ((kt * 4 + g4) ^ (b16 & 7));
        short8 hf = *(const short8*)(Hs + b16 * 1024 + (sp << 4));
        accA = __builtin_amdgcn_mfma_f32_16x16x32_bf16(wA[kt], hf, accA, 0, 0, 0);
        accB = __builtin_amdgcn_mfma_f32_16x16x32_bf16(wB[kt], hf, accB, 0, 0, 0);
      }
    }

    // pointwise: xv = [cellA i,f,g,o | cellB i,f,g,o]
    float iA = fsigmoid(accA[0] + h2f((unsigned short)xv[0]));
    float fA = fsigmoid(accA[1] + h2f((unsigned short)xv[1]));
    float gA = ftanh(accA[2] + h2f((unsigned short)xv[2]));
    float oA = fsigmoid(accA[3] + h2f((unsigned short)xv[3]));
    cA = fA * cA + iA * gA;
    hAv = oA * ftanh(cA);
    float iB = fsigmoid(accB[0] + h2f((unsigned short)xv[4]));
    float fB = fsigmoid(accB[1] + h2f((unsigned short)xv[5]));
    float gB = ftanh(accB[2] + h2f((unsigned short)xv[6]));
    float oB = fsigmoid(accB[3] + h2f((unsigned short)xv[7]));
    cB = fB * cB + iB * gB;
    hBv = oB * ftanh(cB);

    // release = just the tagged stores (8B atomics; dword-atomic tag+data)
    const unsigned tagS = ((unsigned)(t + 1)) << 16;
    float hAp = __shfl_xor(hAv, 16, 64);
    float hBp = __shfl_xor(hBv, 16, 64);
    if ((g4 & 1) == 0) {
      char* hd = hbufT + ((t + 1) & 1) * 131072 + bg * 32768 + b16 * 2048;
      unsigned dA0 = tagS | (unsigned)(unsigned short)f2bf(hAv);
      unsigned dA1 = tagS | (unsigned)(unsigned short)f2bf(hAp);
      unsigned dB0 = tagS | (unsigned)(unsigned short)f2bf(hBv);
      unsigned dB1 = tagS | (unsigned)(unsigned short)f2bf(hBp);
      unsigned long long uA = (unsigned long long)dA0 | ((unsigned long long)dA1 << 32);
      unsigned long long uB = (unsigned long long)dB0 | ((unsigned long long)dB1 << 32);
      __hip_atomic_store((unsigned long long*)(hd + colA * 4), uA, __ATOMIC_RELAXED, __HIP_MEMORY_SCOPE_AGENT);
      __hip_atomic_store((unsigned long long*)(hd + colB * 4), uB, __ATOMIC_RELAXED, __HIP_MEMORY_SCOPE_AGENT);
    }

    // outputs off the critical path
    float* od = outp + ((size_t)t * BB + batchg) * HH;
    od[colA] = hAv;
    od[colB] = hBv;
    xv = xvn;
  }

  // final (h_T, c_T)
  float* hT = outp + (size_t)TT * BB * HH;
  float* cT = hT + (size_t)BB * HH;
  hT[(size_t)batchg * HH + colA] = hAv;
  hT[(size_t)batchg * HH + colB] = hBv;
  cT[(size_t)batchg * HH + colA] = cA;
  cT[(size_t)batchg * HH + colB] = cB;
}

extern "C" void kernel_launch(void* const* d_in, const int* in_sizes, int n_in,
                              void* d_out, int out_size, void* d_ws, size_t ws_size,
                              hipStream_t stream) {
  (void)in_sizes; (void)n_in; (void)out_size; (void)ws_size;
  const float* x = (const float*)d_in[0];
  const float* Wih = (const float*)d_in[1];
  const float* Whh = (const float*)d_in[2];
  const float* bih = (const float*)d_in[3];
  const float* bhh = (const float*)d_in[4];
  float* outp = (float*)d_out;
  char* ws = (char*)d_ws;

  const size_t M = (size_t)TT * BB;  // 131072
  size_t off = 0;
  auto take = [&](size_t sz) { size_t r = off; off = (off + sz + 255) & ~255ULL; return r; };
  const size_t xbf_o = take(M * 512 * 2);
  const size_t wih_o = take((size_t)GG * 512 * 2);
  const size_t hbuf_o = take(2 * 131072);  // tagged h ping-pong, 256 KB
  const size_t xpart_o = take(M * (size_t)GG * 2);

  __hip_bfloat16* xbf = (__hip_bfloat16*)(ws + xbf_o);
  __hip_bfloat16* wihbf = (__hip_bfloat16*)(ws + wih_o);
  __half* xpart = (__half*)(ws + xpart_o);

  // zero tags so no in-launch false-validation (0x0000 != any step tag >= 1)
  hipMemsetAsync(ws + hbuf_o, 0, 2 * 131072, stream);

  cvt_bf16_kernel<<<4096, 256, 0, stream>>>((const float4*)x, (short4v*)xbf, (long)(M * 512 / 4));
  cvt_bf16_kernel<<<256, 256, 0, stream>>>((const float4*)Wih, (short4v*)wihbf, (long)((size_t)GG * 512 / 4));

  gemm_xpart<<<16384, 256, 0, stream>>>(xbf, wihbf, bih, bhh, xpart);
  lstm_scan_kernel<<<64, 256, 0, stream>>>(xpart, Whh, ws + hbuf_o, outp);
}